// Round 7
// baseline (137.973 us; speedup 1.0000x reference)
//
#include <hip/hip_runtime.h>

// Pairwise cosine similarity: C[i][j] = <x_i/||x_i||, y_j/||y_j||>
// x,y: [8192][512] f32.  Out: [8192][8192] f32.
// Stage 1: row-normalize -> bf16 in d_ws (xn 8MB + yn 8MB), single launch.
// Stage 2: 8-phase 256x256 bf16 MFMA GEMM, 4 output tiles per block
//   (grid=256): one continuous 32-K-tile pipeline per block; B-panel
//   advances across tile boundaries with full prefetch.
// R7 fix: mid-loop epilogues are DIRECT scatter stores from acc (no LDS) —
//   R6 NaN'd because its strip window clobbered the live staged B(t+2)
//   panel in buf0-B. Direct stores touch only registers + C; P8's
//   VMCNT(4)+BAR already ordered everything needed. Final tile keeps the
//   R4-proven LDS-strip nt epilogue (all LDS dead after final VMCNT(0)).

typedef __attribute__((ext_vector_type(8))) short bf16x8;
typedef __attribute__((ext_vector_type(4))) float f32x4;
typedef __attribute__((ext_vector_type(8))) unsigned short ushort8;

#define M_DIM 8192
#define N_DIM 8192
#define K_DIM 512

static __device__ __forceinline__ unsigned short f32_to_bf16(float f) {
  unsigned int u = __float_as_uint(f);
  u = (u + 0x7FFFu + ((u >> 16) & 1u)) >> 16;  // round-to-nearest-even
  return (unsigned short)u;
}

// One wave per row; handles x rows [0,8192) and y rows [8192,16384).
__global__ __launch_bounds__(256) void normalize_rows(
    const float* __restrict__ x, const float* __restrict__ y,
    unsigned short* __restrict__ out) {
  const int wid = threadIdx.x >> 6;
  const int lane = threadIdx.x & 63;
  const int row = (blockIdx.x << 2) + wid;
  const float* src = row < M_DIM ? x + (size_t)row * K_DIM
                                 : y + (size_t)(row - M_DIM) * K_DIM;
  const float4* r = (const float4*)src;
  float4 v0 = r[lane * 2];
  float4 v1 = r[lane * 2 + 1];
  float ss = v0.x * v0.x + v0.y * v0.y + v0.z * v0.z + v0.w * v0.w +
             v1.x * v1.x + v1.y * v1.y + v1.z * v1.z + v1.w * v1.w;
#pragma unroll
  for (int off = 32; off; off >>= 1) ss += __shfl_xor(ss, off, 64);
  const float s = 1.0f / fmaxf(sqrtf(ss), 1e-8f);
  const float f[8] = {v0.x, v0.y, v0.z, v0.w, v1.x, v1.y, v1.z, v1.w};
  union { ushort8 v; unsigned short u[8]; } o;
#pragma unroll
  for (int i = 0; i < 8; ++i) o.u[i] = f32_to_bf16(f[i] * s);
  *(ushort8*)(out + (size_t)row * K_DIM + lane * 8) = o.v;
}

static __device__ __forceinline__ void gl16(const unsigned short* g, char* l) {
  __builtin_amdgcn_global_load_lds(
      (const __attribute__((address_space(1))) unsigned int*)g,
      (__attribute__((address_space(3))) unsigned int*)l, 16, 0, 0);
}

#define BAR() __builtin_amdgcn_s_barrier()
#define SBAR() __builtin_amdgcn_sched_barrier(0)
#define LGKM0() do { asm volatile("s_waitcnt lgkmcnt(0)" ::: "memory"); \
                     __builtin_amdgcn_sched_barrier(0); } while (0)
#define VMCNT(n) do { asm volatile("s_waitcnt vmcnt(" #n ")" ::: "memory"); \
                      __builtin_amdgcn_sched_barrier(0); } while (0)

__global__ __launch_bounds__(512, 2) void cosgemm(
    const unsigned short* __restrict__ A,   // xn bf16 [8192][512]
    const unsigned short* __restrict__ B,   // yn bf16 [8192][512]
    float* __restrict__ C) {                // [8192][8192]
  extern __shared__ char smem[];  // 128KB: [parity][op][row-half] 16KB units

  const int tid = threadIdx.x;
  const int lane = tid & 63;
  const int wid = tid >> 6;
  const int wm = wid >> 2;        // 0..1  (M half)
  const int wn = wid & 3;         // 0..3  (N quarter)
  const int lr16 = lane & 15;
  const int hq = lane >> 4;       // 0..3
  const int x7 = lane & 7;

  // grid = 256 (1 block/CU). xcd = bid&7; each XCD: 4 row-bands x 8 col
  // quads. Block covers 4 adjacent 256-col tiles (tau 0..3).
  const int bid = blockIdx.x;
  const int idx = bid >> 3;                 // 0..31
  const int by = ((bid & 7) << 2) + (idx & 3);
  const int bxq = idx >> 2;                 // 0..7
  const int row0 = by << 8;
  const int col0 = bxq << 10;               // 4 tiles x 256 cols

  // staging: row = half*128 + c*64 + tid/8, 16B slot = (tid&7)^(row&7)
  const int rl = tid >> 3;
  const int sl = (tid & 7) ^ (rl & 7);
  const unsigned short* qA[2], * qB[2];
  qA[0] = A + (size_t)(row0 + rl) * K_DIM + sl * 8;
  qA[1] = A + (size_t)(row0 + 64 + rl) * K_DIM + sl * 8;
  qB[0] = B + (size_t)(col0 + rl) * K_DIM + sl * 8;
  qB[1] = B + (size_t)(col0 + 64 + rl) * K_DIM + sl * 8;

  // goff: A -> (T&7)*64 ; B -> (T>>3)*131072 + (T&7)*64  (panel advance)
  auto stage = [&](int op, int half, int par, size_t goff) {
    const unsigned short* g0 = (op ? qB[0] : qA[0]) + goff + half * 65536;
    const unsigned short* g1 = (op ? qB[1] : qA[1]) + goff + half * 65536;
    char* l = smem + (par << 16) + (op << 15) + (half << 14) + (wid << 10);
    gl16(g0, l);
    gl16(g1, l + 8192);
  };

  bf16x8 af[4][2], bf[4][2];
  f32x4 acc[8][4] = {};

  auto ldA = [&](int par, int fmBase) {   // 8 x ds_read_b128
#pragma unroll
    for (int j = 0; j < 4; ++j) {
      const char* base = smem + (par << 16) + (wm << 14) +
                         ((fmBase + j) * 16 + lr16) * 128;
#pragma unroll
      for (int kk = 0; kk < 2; ++kk)
        af[j][kk] = *(const bf16x8*)(base + ((((kk << 2) | hq) ^ x7) << 4));
    }
  };
  auto ldB = [&](int par, int fnBase) {   // 4 x ds_read_b128
#pragma unroll
    for (int j = 0; j < 2; ++j) {
      const char* base = smem + (par << 16) + 32768 + ((wn >> 1) << 14) +
                         (((wn & 1) << 6) + (fnBase + j) * 16 + lr16) * 128;
#pragma unroll
      for (int kk = 0; kk < 2; ++kk)
        bf[fnBase + j][kk] =
            *(const bf16x8*)(base + ((((kk << 2) | hq) ^ x7) << 4));
    }
  };
  auto mm = [&](int fmBase, int fnBase) {  // 16 MFMA
    __builtin_amdgcn_s_setprio(1);
#pragma unroll
    for (int m = 0; m < 4; ++m)
#pragma unroll
      for (int n = 0; n < 2; ++n)
#pragma unroll
        for (int kk = 0; kk < 2; ++kk)
          acc[fmBase + m][fnBase + n] = __builtin_amdgcn_mfma_f32_16x16x32_bf16(
              af[m][kk], bf[fnBase + n][kk], acc[fmBase + m][fnBase + n], 0, 0, 0);
    __builtin_amdgcn_s_setprio(0);
  };

  // mid-loop epilogue: direct scatter stores from acc (registers + C only;
  // no LDS, no sync needed — stores precede next iter's loads in issue
  // order, so later counted-vmcnt waits subsume them).
  auto epi_direct = [&](int tau) {
    const int crow0 = row0 + (wm << 7) + (hq << 2);
    const int ccol0 = col0 + (tau << 8) + (wn << 6) + lr16;
#pragma unroll
    for (int fm = 0; fm < 8; ++fm)
#pragma unroll
      for (int fn = 0; fn < 4; ++fn)
#pragma unroll
        for (int q = 0; q < 4; ++q)
          C[(size_t)(crow0 + fm * 16 + q) * N_DIM + ccol0 + (fn << 4)] =
              acc[fm][fn][q];
  };

  // final-tile epilogue: per-wave [16][68] f32 strip in [32K,96K) — all
  // LDS is dead here (after final VMCNT(0) + all ds reads consumed).
  auto epi_strip = [&](int tau) {
    float* S = (float*)(smem + 32768 + (wid << 13));
    const int crow0 = row0 + (wm << 7);
    const int ccol0 = col0 + (tau << 8) + (wn << 6);
#pragma unroll
    for (int fm = 0; fm < 8; ++fm) {
#pragma unroll
      for (int fn = 0; fn < 4; ++fn)
#pragma unroll
        for (int q = 0; q < 4; ++q)
          S[(hq * 4 + q) * 68 + fn * 16 + lr16] = acc[fm][fn][q];
#pragma unroll
      for (int r = 0; r < 4; ++r) {
        f32x4 v = *(const f32x4*)&S[(r * 4 + hq) * 68 + lr16 * 4];
        __builtin_nontemporal_store(
            v, (f32x4*)&C[(size_t)(crow0 + fm * 16 + r * 4 + hq) * N_DIM +
                          ccol0 + lr16 * 4]);
      }
    }
  };

  // ---- prologue: T0.A, T0.B, T1.B; confirm T0 landed
  stage(0, 0, 0, 0); stage(0, 1, 0, 0);
  stage(1, 0, 0, 0); stage(1, 1, 0, 0);
  stage(1, 0, 1, 64); stage(1, 1, 1, 64);
  VMCNT(4);
  BAR(); SBAR();

#pragma unroll 1
  for (int j = 0; j < 16; ++j) {
    const bool st = (j < 15);
    const int t2 = 2 * j + 2, t3 = 2 * j + 3;
    const size_t gA_u = (size_t)((2 * j + 1) & 7) * 64;
    const size_t gA_2 = (size_t)(t2 & 7) * 64;
    const size_t gB_2 = (size_t)(t2 >> 3) * 131072 + (size_t)(t2 & 7) * 64;
    const size_t gB_3 = (size_t)(t3 >> 3) * 131072 + (size_t)(t3 & 7) * 64;
    // parities: t even -> 0, u odd -> 1, t+2 -> 0, t+3 -> 1
    // P1
    ldA(0, 0); ldB(0, 0); stage(0, 0, 1, gA_u);
    BAR(); LGKM0(); mm(0, 0); BAR();
    // P2
    ldB(0, 2); stage(0, 1, 1, gA_u);
    BAR(); LGKM0(); mm(0, 2); BAR();
    // P3
    ldA(0, 4); if (st) stage(1, 0, 0, gB_2);
    BAR(); LGKM0(); mm(4, 0); BAR();
    // P4
    if (st) stage(1, 1, 0, gB_2);
    BAR(); LGKM0(); mm(4, 2);
    if (st) { VMCNT(4); } else { VMCNT(0); }
    BAR(); SBAR();
    // P5
    ldA(1, 0); ldB(1, 0); if (st) stage(0, 0, 0, gA_2);
    BAR(); LGKM0(); mm(0, 0); BAR();
    // P6
    ldB(1, 2); if (st) stage(0, 1, 0, gA_2);
    BAR(); LGKM0(); mm(0, 2); BAR();
    // P7
    ldA(1, 4); if (st) stage(1, 0, 1, gB_3);
    BAR(); LGKM0(); mm(4, 0); BAR();
    // P8
    if (st) stage(1, 1, 1, gB_3);
    BAR(); LGKM0(); mm(4, 2);
    if (st) { VMCNT(4); }
    BAR(); SBAR();
    // tile boundary: direct-store epilogue, then reset acc
    if ((j & 3) == 3 && j < 15) {
      epi_direct(j >> 2);
#pragma unroll
      for (int fm = 0; fm < 8; ++fm)
#pragma unroll
        for (int fn = 0; fn < 4; ++fn)
          acc[fm][fn] = (f32x4){0.f, 0.f, 0.f, 0.f};
    }
  }
  // final tile: strip epilogue (LDS all dead)
  epi_strip(3);
}

extern "C" void kernel_launch(void* const* d_in, const int* in_sizes, int n_in,
                              void* d_out, int out_size, void* d_ws, size_t ws_size,
                              hipStream_t stream) {
  const float* x = (const float*)d_in[0];
  const float* y = (const float*)d_in[1];
  float* out = (float*)d_out;
  unsigned short* xn = (unsigned short*)d_ws;                    // 8 MB
  unsigned short* yn = xn + (size_t)M_DIM * K_DIM;               // 8 MB

  (void)hipFuncSetAttribute((const void*)cosgemm,
                            hipFuncAttributeMaxDynamicSharedMemorySize, 131072);

  normalize_rows<<<(M_DIM + N_DIM) / 4, 256, 0, stream>>>(x, y, xn);
  cosgemm<<<256, 512, 131072, stream>>>(xn, yn, out);
}

// Round 9
// 109.500 us; speedup vs baseline: 1.2600x; 1.2600x over previous
//
#include <hip/hip_runtime.h>

// Pairwise cosine similarity: C[i][j] = <x_i/||x_i||, y_j/||y_j||>
// x,y: [8192][512] f32.  Out: [8192][8192] f32.
// Stage 1: row-normalize -> bf16 in d_ws (fused single launch).
// Stage 2: 256x128-tile BK=32 8-phase bf16 MFMA GEMM, 4 waves/block,
//   48KB LDS double-buffer -> 2 blocks/CU (TLP hides fill/drain/barrier
//   stalls that R4's 1-block/CU 128KB config fully exposed).
//   Counted VMCNT(2) (uniform), XOR-swizzled staging (4-slot rows,
//   2-way residual = free), XCD 4-band ordering, end-of-loop strip
//   epilogue with nt stores (R4-proven; NO mid-loop epilogues — R7/R8
//   showed stores inside a counted-vmcnt stream serialize, and strips
//   in "dead" regions failed twice).

typedef __attribute__((ext_vector_type(8))) short bf16x8;
typedef __attribute__((ext_vector_type(4))) float f32x4;
typedef __attribute__((ext_vector_type(8))) unsigned short ushort8;

#define M_DIM 8192
#define N_DIM 8192
#define K_DIM 512

static __device__ __forceinline__ unsigned short f32_to_bf16(float f) {
  unsigned int u = __float_as_uint(f);
  u = (u + 0x7FFFu + ((u >> 16) & 1u)) >> 16;  // round-to-nearest-even
  return (unsigned short)u;
}

// One wave per row; handles x rows [0,8192) and y rows [8192,16384).
__global__ __launch_bounds__(256) void normalize_rows(
    const float* __restrict__ x, const float* __restrict__ y,
    unsigned short* __restrict__ out) {
  const int wid = threadIdx.x >> 6;
  const int lane = threadIdx.x & 63;
  const int row = (blockIdx.x << 2) + wid;
  const float* src = row < M_DIM ? x + (size_t)row * K_DIM
                                 : y + (size_t)(row - M_DIM) * K_DIM;
  const float4* r = (const float4*)src;
  float4 v0 = r[lane * 2];
  float4 v1 = r[lane * 2 + 1];
  float ss = v0.x * v0.x + v0.y * v0.y + v0.z * v0.z + v0.w * v0.w +
             v1.x * v1.x + v1.y * v1.y + v1.z * v1.z + v1.w * v1.w;
#pragma unroll
  for (int off = 32; off; off >>= 1) ss += __shfl_xor(ss, off, 64);
  const float s = 1.0f / fmaxf(sqrtf(ss), 1e-8f);
  const float f[8] = {v0.x, v0.y, v0.z, v0.w, v1.x, v1.y, v1.z, v1.w};
  union { ushort8 v; unsigned short u[8]; } o;
#pragma unroll
  for (int i = 0; i < 8; ++i) o.u[i] = f32_to_bf16(f[i] * s);
  *(ushort8*)(out + (size_t)row * K_DIM + lane * 8) = o.v;
}

static __device__ __forceinline__ void gl16(const unsigned short* g, char* l) {
  __builtin_amdgcn_global_load_lds(
      (const __attribute__((address_space(1))) unsigned int*)g,
      (__attribute__((address_space(3))) unsigned int*)l, 16, 0, 0);
}

#define BAR() __builtin_amdgcn_s_barrier()
#define SBAR() __builtin_amdgcn_sched_barrier(0)
#define LGKM0() do { asm volatile("s_waitcnt lgkmcnt(0)" ::: "memory"); \
                     __builtin_amdgcn_sched_barrier(0); } while (0)
#define VMCNT(n) do { asm volatile("s_waitcnt vmcnt(" #n ")" ::: "memory"); \
                      __builtin_amdgcn_sched_barrier(0); } while (0)

// LDS per parity p: base p*24576; A [0,16K): row r (0..255) at r*64,
// slot s (16B) stored at (s ^ (r&3))*16; B [16K,24K): row (0..127) same.
__global__ __launch_bounds__(256, 2) void cosgemm(
    const unsigned short* __restrict__ A,   // xn bf16 [8192][512]
    const unsigned short* __restrict__ B,   // yn bf16 [8192][512]
    float* __restrict__ C) {                // [8192][8192]
  extern __shared__ char smem[];  // 49152 B

  const int tid = threadIdx.x;
  const int lane = tid & 63;
  const int wid = tid >> 6;       // 0..3
  const int wm = wid >> 1;        // 0..1  (M half: 128 rows)
  const int wn = wid & 1;         // 0..1  (N half: 64 cols)
  const int lr16 = lane & 15;
  const int hq = lane >> 4;       // 0..3  (k slot)
  const int sw = hq ^ (lr16 & 3); // swizzled ds_read slot (uniform/lane)

  // XCD banding: xcd = bid&7 owns by in {4x..4x+3}; sweep bx (64) per band.
  const int bid = blockIdx.x;                // 0..2047
  const int idx = bid >> 3;                  // 0..255
  const int by = ((bid & 7) << 2) + (idx & 3);   // 0..31
  const int bx = idx >> 2;                   // 0..63
  const int row0 = by << 8;                  // A rows (256)
  const int col0 = bx << 7;                  // B rows / C cols (128)

  // staging source: call covers row = base + c*16 + (lane>>2),
  // global 16B slot = (lane&3) ^ (row&3) = (lane&3) ^ ((lane>>2)&3).
  const int srl = lane >> 2;
  const int ssl = (lane & 3) ^ (srl & 3);
  const unsigned short* pA =
      A + (size_t)(row0 + (wid << 6) + srl) * K_DIM + ssl * 8;
  const unsigned short* pB =
      B + (size_t)(col0 + (wid << 5) + srl) * K_DIM + ssl * 8;

  // stageA2: 2 gl16 (32 rows); stageB1: 1 gl16 (16 rows). T = K-tile idx.
  auto stageA2 = [&](int par, int cpair, int T) {
    char* l = smem + par * 24576 + (wid << 12) + (cpair << 11);
    const unsigned short* g = pA + T * 32 + (size_t)(cpair << 5) * K_DIM;
    gl16(g, l);
    gl16(g + (size_t)16 * K_DIM, l + 1024);
  };
  auto stageB1 = [&](int par, int c, int T) {
    char* l = smem + par * 24576 + 16384 + (wid << 11) + (c << 10);
    gl16(pB + T * 32 + (size_t)(c << 4) * K_DIM, l);
  };

  bf16x8 af[4], bf[4];
  f32x4 acc[8][4] = {};

  auto ldA = [&](int par, int fmBase) {   // 4 x ds_read_b128
#pragma unroll
    for (int j = 0; j < 4; ++j) {
      const int row = (wm << 7) + (fmBase + j) * 16 + lr16;
      af[j] = *(const bf16x8*)(smem + par * 24576 + row * 64 + (sw << 4));
    }
  };
  auto ldB = [&](int par, int fnBase) {   // 2 x ds_read_b128
#pragma unroll
    for (int j = 0; j < 2; ++j) {
      const int row = (wn << 6) + (fnBase + j) * 16 + lr16;
      bf[fnBase + j] =
          *(const bf16x8*)(smem + par * 24576 + 16384 + row * 64 + (sw << 4));
    }
  };
  auto mm = [&](int fmBase, int fnBase) {  // 8 MFMA
    __builtin_amdgcn_s_setprio(1);
#pragma unroll
    for (int m = 0; m < 4; ++m)
#pragma unroll
      for (int n = 0; n < 2; ++n)
        acc[fmBase + m][fnBase + n] = __builtin_amdgcn_mfma_f32_16x16x32_bf16(
            af[m], bf[fnBase + n], acc[fmBase + m][fnBase + n], 0, 0, 0);
    __builtin_amdgcn_s_setprio(0);
  };

  // ---- prologue: A(0), B(0), B(1); VMCNT(2) -> tile0 landed
  stageA2(0, 0, 0); stageA2(0, 1, 0);
  stageB1(0, 0, 0); stageB1(0, 1, 0);
  stageB1(1, 0, 1); stageB1(1, 1, 1);
  VMCNT(2);
  BAR(); SBAR();

  // per-wave outstanding tracking (issue order, in-order retirement):
  // steady P4: B(u)2,A(u)4,B(t+2)2=8 -> VMCNT(2) leaves B(t+2).
  // steady P8: B(t+2)2,A(t+2)4,B(t+3)2=8 -> VMCNT(2) leaves B(t+3).
#pragma unroll 1
  for (int j = 0; j < 8; ++j) {
    const bool st = (j < 7);
    const int u = 2 * j + 1, t2 = 2 * j + 2, t3 = 2 * j + 3;
    // P1
    ldA(0, 0); ldB(0, 0); stageA2(1, 0, u);
    BAR(); LGKM0(); mm(0, 0); BAR();
    // P2
    ldB(0, 2); stageA2(1, 1, u);
    BAR(); LGKM0(); mm(0, 2); BAR();
    // P3
    ldA(0, 4); if (st) stageB1(0, 0, t2);
    BAR(); LGKM0(); mm(4, 0); BAR();
    // P4
    if (st) stageB1(0, 1, t2);
    BAR(); LGKM0(); mm(4, 2);
    if (st) { VMCNT(2); } else { VMCNT(0); }
    BAR(); SBAR();
    // P5
    ldA(1, 0); ldB(1, 0); if (st) stageA2(0, 0, t2);
    BAR(); LGKM0(); mm(0, 0); BAR();
    // P6
    ldB(1, 2); if (st) stageA2(0, 1, t2);
    BAR(); LGKM0(); mm(0, 2); BAR();
    // P7
    ldA(1, 4); if (st) stageB1(1, 0, t3);
    BAR(); LGKM0(); mm(4, 0); BAR();
    // P8
    if (st) stageB1(1, 1, t3);
    BAR(); LGKM0(); mm(4, 2);
    if (st) { VMCNT(2); }
    BAR(); SBAR();
  }

  // ---- epilogue: per-wave [16][68] f32 strip (4352B) at smem+wid*4352
  // (all LDS dead: j=7 staged nothing new, VMCNT(0) at its P4, last ds
  // reads consumed, and every wave passed the final barrier).
  float* S = (float*)(smem + wid * 4352);
  const int crow0 = row0 + (wm << 7);
  const int ccol0 = col0 + (wn << 6);
#pragma unroll
  for (int fm = 0; fm < 8; ++fm) {
#pragma unroll
    for (int fn = 0; fn < 4; ++fn)
#pragma unroll
      for (int q = 0; q < 4; ++q)
        S[(hq * 4 + q) * 68 + fn * 16 + lr16] = acc[fm][fn][q];
#pragma unroll
    for (int r = 0; r < 4; ++r) {
      f32x4 v = *(const f32x4*)&S[(r * 4 + hq) * 68 + lr16 * 4];
      __builtin_nontemporal_store(
          v, (f32x4*)&C[(size_t)(crow0 + fm * 16 + r * 4 + hq) * N_DIM +
                        ccol0 + lr16 * 4]);
    }
  }
}

extern "C" void kernel_launch(void* const* d_in, const int* in_sizes, int n_in,
                              void* d_out, int out_size, void* d_ws, size_t ws_size,
                              hipStream_t stream) {
  const float* x = (const float*)d_in[0];
  const float* y = (const float*)d_in[1];
  float* out = (float*)d_out;
  unsigned short* xn = (unsigned short*)d_ws;                    // 8 MB
  unsigned short* yn = xn + (size_t)M_DIM * K_DIM;               // 8 MB

  (void)hipFuncSetAttribute((const void*)cosgemm,
                            hipFuncAttributeMaxDynamicSharedMemorySize, 65536);

  normalize_rows<<<(M_DIM + N_DIM) / 4, 256, 0, stream>>>(x, y, xn);
  cosgemm<<<(M_DIM / 256) * (N_DIM / 128), 256, 49152, stream>>>(xn, yn, out);
}